// Round 3
// baseline (92.745 us; speedup 1.0000x reference)
//
#include <hip/hip_runtime.h>

// Voxel merge (2x2x2, blocks i*4+j*2+k) + mask + LayerNorm(768) + GEMM [65536,768]x[768,192] (bf16 MFMA).
// Structure: 16 merged rows/block, raw x DMA'd to LDS via global_load_lds (MLP via vmcnt queue),
// bf16 A-tile overlaid in place, MFMA with L2-resident pre-packed W, coalesced C store via LDS.
#define NOUT 192
#define M_TOTAL 65536
#define OUT0 (M_TOTAL * NOUT)
#define CSTRIDE 196   // padded f32 C-row stride

typedef __attribute__((ext_vector_type(8))) short  short8;
typedef __attribute__((ext_vector_type(4))) float  f32x4;
typedef __attribute__((ext_vector_type(4))) unsigned short us4;

__device__ __forceinline__ unsigned short f2bf(float f) {
    union { float f; unsigned u; } a; a.f = f;
    unsigned r = a.u + 0x7FFFu + ((a.u >> 16) & 1u);  // RNE
    return (unsigned short)(r >> 16);
}

__device__ __forceinline__ void gload16(void* lds, const void* g) {
    __builtin_amdgcn_global_load_lds((const __attribute__((address_space(1))) void*)g,
                                     (__attribute__((address_space(3))) void*)lds, 16, 0, 0);
}

// Pre-pack W [768][192] fp32 -> bf16 in per-lane MFMA B-fragment order:
// Wb[((ks*12 + fn)*64 + l)*8 + e] = bf16(W[(ks*32 + (l>>4)*8 + e)*192 + fn*16 + (l&15)])
__global__ __launch_bounds__(256) void prepw_kernel(const float* __restrict__ Wm,
                                                    unsigned short* __restrict__ Wb) {
    int t = blockIdx.x * 256 + threadIdx.x;
    if (t >= 24 * 12 * 512) return;
    int e  = t & 7;
    int l  = (t >> 3) & 63;
    int f  = t >> 9;
    int fn = f % 12;
    int ks = f / 12;
    Wb[t] = f2bf(Wm[(ks * 32 + ((l >> 4) << 3) + e) * NOUT + fn * 16 + (l & 15)]);
}

__global__ __launch_bounds__(256, 3) void fused_kernel(
    const float* __restrict__ x, const float* __restrict__ mask,
    const float* __restrict__ gamma, const float* __restrict__ beta,
    const unsigned short* __restrict__ Wb, float* __restrict__ out)
{
    // rawf: 16 rows x 768 f32 (3072 B/row). Phase 2 overlays the bf16 A-tile into
    // each row's first 1536 B (wave-private rows, barrier-separated from MFMA).
    // Phase 4 overlays the 16x196 f32 C-tile (barrier-separated).
    __shared__ __align__(16) float rawf[16 * 768];   // 48 KiB
    __shared__ __align__(16) float maskLds[16 * 8];  // 512 B

    const int tid = threadIdx.x;
    const int l   = tid & 63;
    const int wv  = tid >> 6;            // 0..3
    const int rowbase = blockIdx.x * 16;

    // Per-lane merged-channel constants (independent of row): c8 = m*256 + 4l
    int bi_[3], ch_[3], vo_[3];
#pragma unroll
    for (int m = 0; m < 3; ++m) {
        const int c8 = (m << 8) + (l << 2);
        const int bi = c8 / 96;                      // sub-voxel block (i*4+j*2+k)
        bi_[m] = bi;
        ch_[m] = c8 - bi * 96;
        vo_[m] = ((bi >> 2) << 12) + (((bi >> 1) & 1) << 6) + (bi & 1);  // i*4096 + j*64 + k
    }

    // ---------------- DMA: raw x -> LDS (12 async 1KB wave-issues per wave) ----------------
#pragma unroll
    for (int rr = 0; rr < 4; ++rr) {
        const int r  = (wv << 2) + rr;
        const int rg = rowbase + r;
        const int w2 = rg & 31, h2 = (rg >> 5) & 31, d2 = (rg >> 10) & 31, b = rg >> 15;
        const int vbase = ((b * 64 + d2 * 2) * 64 + h2 * 2) * 64 + w2 * 2;
#pragma unroll
        for (int m = 0; m < 3; ++m)
            gload16(&rawf[r * 768 + (m << 8)],
                    x + (size_t)(vbase + vo_[m]) * 96 + ch_[m]);
    }

    // mask staging: 16 rows x 8 sub-voxels
    if (tid < 128) {
        const int r = tid >> 3, bi = tid & 7;
        const int rg = rowbase + r;
        const int w2 = rg & 31, h2 = (rg >> 5) & 31, d2 = (rg >> 10) & 31, b = rg >> 15;
        const int vbase = ((b * 64 + d2 * 2) * 64 + h2 * 2) * 64 + w2 * 2;
        maskLds[tid] = mask[vbase + ((bi >> 2) << 12) + (((bi >> 1) & 1) << 6) + (bi & 1)];
    }

    // gamma/beta preload (lane-fixed channels, reused for all rows)
    float4 g_[3], be_[3];
#pragma unroll
    for (int m = 0; m < 3; ++m) {
        const int c8 = (m << 8) + (l << 2);
        g_[m]  = *(const float4*)(gamma + c8);
        be_[m] = *(const float4*)(beta  + c8);
    }

    __syncthreads();   // drains vmcnt: all raw rows + masks visible

    // mask_out
    if (tid < 16) {
        float ms = 0.f;
#pragma unroll
        for (int i = 0; i < 8; ++i) ms += maskLds[tid * 8 + i];
        out[OUT0 + rowbase + tid] = (ms > 0.f) ? 1.0f : 0.0f;
    }

    // ---------------- Stats + normalize (each wave: its own 4 rows) ----------------
    float4 vs[4][3];
    float  s[4], s2[4];
#pragma unroll
    for (int rr = 0; rr < 4; ++rr) {
        const int r = (wv << 2) + rr;
#pragma unroll
        for (int m = 0; m < 3; ++m) {
            float4 v = *(const float4*)&rawf[r * 768 + (m << 8) + (l << 2)];
            const float mk = maskLds[r * 8 + bi_[m]];
            v.x *= mk; v.y *= mk; v.z *= mk; v.w *= mk;
            vs[rr][m] = v;
        }
        float a = 0.f, b2 = 0.f;
#pragma unroll
        for (int m = 0; m < 3; ++m) {
            const float4 v = vs[rr][m];
            a  += (v.x + v.y) + (v.z + v.w);
            b2 += (v.x * v.x + v.y * v.y) + (v.z * v.z + v.w * v.w);
        }
        s[rr] = a; s2[rr] = b2;
    }
    // 8 interleaved butterfly chains (4 rows x {s, s2})
#pragma unroll
    for (int off = 32; off >= 1; off >>= 1) {
#pragma unroll
        for (int rr = 0; rr < 4; ++rr) {
            s[rr]  += __shfl_xor(s[rr],  off);
            s2[rr] += __shfl_xor(s2[rr], off);
        }
    }
    // normalize -> bf16 A-tile overlaid into rawf (row-private, swizzled by (r&7)<<4)
#pragma unroll
    for (int rr = 0; rr < 4; ++rr) {
        const int r = (wv << 2) + rr;
        const float mu  = s[rr] * (1.f / 768.f);
        const float var = s2[rr] * (1.f / 768.f) - mu * mu;
        const float rs  = rsqrtf(var + 1e-5f);
        char* abase = (char*)rawf + r * 3072;
        const int swz = (r & 7) << 4;
#pragma unroll
        for (int m = 0; m < 3; ++m) {
            const float4 v = vs[rr][m];
            us4 o;
            o.x = f2bf((v.x - mu) * rs * g_[m].x + be_[m].x);
            o.y = f2bf((v.y - mu) * rs * g_[m].y + be_[m].y);
            o.z = f2bf((v.z - mu) * rs * g_[m].z + be_[m].z);
            o.w = f2bf((v.w - mu) * rs * g_[m].w + be_[m].w);
            *(us4*)(abase + (((m << 9) + (l << 3)) ^ swz)) = o;   // 8B, wave-linear
        }
    }
    __syncthreads();

    // ---------------- MFMA: [16 x 192] += A[16x768] * W[768x192] ----------------
    f32x4 acc[3] = {};
    const int lrow = l & 15;
    const int kq   = (l >> 4) << 4;
    const int aswz = (lrow & 7) << 4;
    const char* aBase = (const char*)rawf + lrow * 3072;
    const short8* Wv = (const short8*)Wb;
    const int bbase = wv * 192 + l;      // wave owns col-frags 3*wv..3*wv+2

#pragma unroll 4
    for (int ks = 0; ks < 24; ++ks) {
        const short8 a  = *(const short8*)(aBase + ((((ks << 6) + kq)) ^ aswz));
        const short8 b0 = Wv[ks * 768 + bbase];
        const short8 b1 = Wv[ks * 768 + bbase + 64];
        const short8 b2 = Wv[ks * 768 + bbase + 128];
        acc[0] = __builtin_amdgcn_mfma_f32_16x16x32_bf16(a, b0, acc[0], 0, 0, 0);
        acc[1] = __builtin_amdgcn_mfma_f32_16x16x32_bf16(a, b1, acc[1], 0, 0, 0);
        acc[2] = __builtin_amdgcn_mfma_f32_16x16x32_bf16(a, b2, acc[2], 0, 0, 0);
    }

    __syncthreads();   // all A-reads done; rawf becomes the C tile
    // C/D layout: col = lane&15, row = (lane>>4)*4 + j
    float* Clds = rawf;
#pragma unroll
    for (int c = 0; c < 3; ++c)
#pragma unroll
        for (int j = 0; j < 4; ++j)
            Clds[(((l >> 4) << 2) + j) * CSTRIDE + wv * 48 + c * 16 + lrow] = acc[c][j];
    __syncthreads();

    // cooperative fully-coalesced float4 store (exactly 3 iters: 768 float4 / 256 threads)
#pragma unroll
    for (int idx = tid; idx < 16 * 48; idx += 256) {
        const int row = idx / 48, c4 = idx % 48;
        *(float4*)&out[(size_t)(rowbase + row) * NOUT + (c4 << 2)] =
            *(const float4*)&Clds[row * CSTRIDE + (c4 << 2)];
    }
}

extern "C" void kernel_launch(void* const* d_in, const int* in_sizes, int n_in,
                              void* d_out, int out_size, void* d_ws, size_t ws_size,
                              hipStream_t stream) {
    const float* x     = (const float*)d_in[0];
    const float* mask  = (const float*)d_in[1];
    const float* gamma = (const float*)d_in[2];
    const float* beta  = (const float*)d_in[3];
    const float* Wm    = (const float*)d_in[4];
    float* out = (float*)d_out;
    unsigned short* Wb = (unsigned short*)d_ws;   // 294912 B scratch

    prepw_kernel<<<576, 256, 0, stream>>>(Wm, Wb);
    fused_kernel<<<4096, 256, 0, stream>>>(x, mask, gamma, beta, Wb, out);
}